// Round 1
// baseline (2666.044 us; speedup 1.0000x reference)
//
#include <hip/hip_runtime.h>

#define EPSV 1e-5f

// ---- degree: deg[dst] += 1 over all edges -------------------------------
__global__ __launch_bounds__(256) void k_deg(const int* __restrict__ dst,
                                             float* __restrict__ deg, int E) {
    int i = blockIdx.x * 256 + threadIdx.x;
    if (i < E) unsafeAtomicAdd(&deg[dst[i]], 1.0f);
}

// ---- dinv = rsqrt(deg + 1)  (self loop) ---------------------------------
__global__ __launch_bounds__(256) void k_dinv(float* __restrict__ deg, int N) {
    int i = blockIdx.x * 256 + threadIdx.x;
    if (i < N) deg[i] = rsqrtf(deg[i] + 1.0f);
}

// ---- h0 = relu(x @ W_in + b_in); wave per node, lane = out feature ------
__global__ __launch_bounds__(256) void k_input(const float* __restrict__ x,
                                               const float* __restrict__ Win,
                                               const float* __restrict__ bin,
                                               float* __restrict__ h, int N) {
    int t = blockIdx.x * 256 + threadIdx.x;
    int node = t >> 6, j = t & 63;
    if (node >= N) return;
    const float* xr = x + node * 12;
    float acc = bin[j];
#pragma unroll
    for (int k = 0; k < 12; k++) acc = fmaf(xr[k], Win[k * 64 + j], acc);
    h[t] = fmaxf(acc, 0.0f);
}

// ---- hlin = h @ W ; h <- hlin*self_norm + b (agg init, in place) --------
// wave per row; lane j holds W column j in 64 VGPRs; row via wave-uniform
// float4 broadcast loads. In-place h overwrite is safe: each row is touched
// by exactly one wave, and the store depends on all 16 row loads.
__global__ __launch_bounds__(256) void k_gemm(const float* __restrict__ W,
                                              const float* __restrict__ b,
                                              const float* __restrict__ dinv,
                                              float* __restrict__ h,
                                              float* __restrict__ hlin, int N) {
    int j = threadIdx.x & 63;
    float w[64];
#pragma unroll
    for (int k = 0; k < 64; k++) w[k] = W[k * 64 + j];
    float bj = b[j];
    int wave = (blockIdx.x * 256 + threadIdx.x) >> 6;
    int nw = (gridDim.x * 256) >> 6;
    for (int node = wave; node < N; node += nw) {
        const float4* row = (const float4*)(h + node * 64);
        float acc = 0.0f;
#pragma unroll
        for (int kk = 0; kk < 16; kk++) {
            float4 r = row[kk];
            acc = fmaf(r.x, w[4 * kk + 0], acc);
            acc = fmaf(r.y, w[4 * kk + 1], acc);
            acc = fmaf(r.z, w[4 * kk + 2], acc);
            acc = fmaf(r.w, w[4 * kk + 3], acc);
        }
        float d = dinv[node];
        hlin[node * 64 + j] = acc;
        h[node * 64 + j] = fmaf(acc, d * d, bj);
    }
}

// ---- edge scatter: agg[dst] += dinv[src]*dinv[dst] * hlin[src] ----------
// one wave per edge, lane = feature; 64 scalar fp32 HW atomics per edge.
__global__ __launch_bounds__(256) void k_edge(const int* __restrict__ src,
                                              const int* __restrict__ dst,
                                              const float* __restrict__ dinv,
                                              const float* __restrict__ hlin,
                                              float* __restrict__ agg, int E) {
    int wave = (blockIdx.x * 256 + threadIdx.x) >> 6;
    int lane = threadIdx.x & 63;
    if (wave >= E) return;
    int s = src[wave], d = dst[wave];
    float nrm = dinv[s] * dinv[d];
    float v = hlin[s * 64 + lane];
    unsafeAtomicAdd(&agg[d * 64 + lane], v * nrm);
}

// ---- BN stats: per-feature sum and sum-of-squares -----------------------
__global__ __launch_bounds__(256) void k_stats(const float* __restrict__ h,
                                               float* __restrict__ stats, int N) {
    int j = threadIdx.x & 63, grp = threadIdx.x >> 6;
    float s = 0.0f, s2 = 0.0f;
    for (int node = blockIdx.x * 4 + grp; node < N; node += gridDim.x * 4) {
        float v = h[node * 64 + j];
        s += v;
        s2 = fmaf(v, v, s2);
    }
    __shared__ float ls[8][64];
    ls[grp][j] = s;
    ls[4 + grp][j] = s2;
    __syncthreads();
    if (threadIdx.x < 64) {
        float a = ls[0][j] + ls[1][j] + ls[2][j] + ls[3][j];
        float a2 = ls[4][j] + ls[5][j] + ls[6][j] + ls[7][j];
        unsafeAtomicAdd(&stats[j], a);
        unsafeAtomicAdd(&stats[64 + j], a2);
    }
}

// ---- BN normalize (+ optional relu), in place ---------------------------
__global__ __launch_bounds__(256) void k_norm(float* __restrict__ h,
                                              const float* __restrict__ stats,
                                              const float* __restrict__ gamma,
                                              const float* __restrict__ beta,
                                              int total, float invN, int relu) {
    int t = blockIdx.x * 256 + threadIdx.x;
    if (t >= total) return;
    int j = t & 63;
    float mu = stats[j] * invN;
    float var = fmaf(-mu, mu, stats[64 + j] * invN);
    float sc = rsqrtf(var + EPSV) * gamma[j];
    float v = fmaf(h[t] - mu, sc, beta[j]);
    if (relu) v = fmaxf(v, 0.0f);
    h[t] = v;
}

// ---- classifier: out = relu(h@W1+b1) @ W2 + b2 --------------------------
// wave handles 2 nodes (32 lanes each); lane jj holds W1 column jj in regs;
// final 32->2 reduction via half-wave butterfly shuffles.
__global__ __launch_bounds__(256) void k_cls(const float* __restrict__ h,
                                             const float* __restrict__ W1,
                                             const float* __restrict__ b1,
                                             const float* __restrict__ W2,
                                             const float* __restrict__ b2,
                                             float* __restrict__ out, int N) {
    int lane = threadIdx.x & 63;
    int half = lane >> 5, jj = lane & 31;
    float w[64];
#pragma unroll
    for (int k = 0; k < 64; k++) w[k] = W1[k * 32 + jj];
    float bj = b1[jj];
    float w20 = W2[jj * 2 + 0], w21 = W2[jj * 2 + 1];
    float b20 = b2[0], b21 = b2[1];
    int wave = (blockIdx.x * 256 + threadIdx.x) >> 6;
    int nw = (gridDim.x * 256) >> 6;
    for (int base = wave * 2; base < N; base += nw * 2) {
        int node = base + half;
        int vnode = node < N ? node : 0;
        const float4* row = (const float4*)(h + vnode * 64);
        float acc = bj;
#pragma unroll
        for (int kk = 0; kk < 16; kk++) {
            float4 r = row[kk];
            acc = fmaf(r.x, w[4 * kk + 0], acc);
            acc = fmaf(r.y, w[4 * kk + 1], acc);
            acc = fmaf(r.z, w[4 * kk + 2], acc);
            acc = fmaf(r.w, w[4 * kk + 3], acc);
        }
        float h2 = fmaxf(acc, 0.0f);
        float t0 = h2 * w20, t1 = h2 * w21;
#pragma unroll
        for (int m = 1; m <= 16; m <<= 1) {  // stays within the 32-lane half
            t0 += __shfl_xor(t0, m, 64);
            t1 += __shfl_xor(t1, m, 64);
        }
        if (jj == 0 && node < N) {
            ((float2*)out)[node] = make_float2(t0 + b20, t1 + b21);
        }
    }
}

extern "C" void kernel_launch(void* const* d_in, const int* in_sizes, int n_in,
                              void* d_out, int out_size, void* d_ws, size_t ws_size,
                              hipStream_t stream) {
    const float* x     = (const float*)d_in[0];
    const int*   ei    = (const int*)d_in[1];
    const float* Win   = (const float*)d_in[2];
    const float* bin   = (const float*)d_in[3];
    const float* Wg    = (const float*)d_in[4];
    const float* bg    = (const float*)d_in[5];
    const float* gamma = (const float*)d_in[6];
    const float* beta  = (const float*)d_in[7];
    const float* W1    = (const float*)d_in[8];
    const float* b1    = (const float*)d_in[9];
    const float* W2    = (const float*)d_in[10];
    const float* b2    = (const float*)d_in[11];
    float* out = (float*)d_out;

    int N = in_sizes[0] / 12;
    int E = in_sizes[1] / 2;
    const int* src = ei;
    const int* dst = ei + E;

    char* ws = (char*)d_ws;
    size_t szh = (size_t)N * 64 * sizeof(float);
    float* bufA  = (float*)ws;                 // h / agg (in place)
    float* bufB  = (float*)(ws + szh);         // hlin
    float* dinv  = (float*)(ws + 2 * szh);     // deg -> dinv
    size_t dinv_b = (((size_t)N * sizeof(float)) + 255) / 256 * 256;
    float* stats = (float*)(ws + 2 * szh + dinv_b);  // 3 * 128 floats

    hipMemsetAsync(dinv, 0, (size_t)N * sizeof(float), stream);
    hipMemsetAsync(stats, 0, 3 * 128 * sizeof(float), stream);

    k_deg<<<(E + 255) / 256, 256, 0, stream>>>(dst, dinv, E);
    k_dinv<<<(N + 255) / 256, 256, 0, stream>>>(dinv, N);
    k_input<<<(N * 64 + 255) / 256, 256, 0, stream>>>(x, Win, bin, bufA, N);

    float invN = 1.0f / (float)N;
    for (int i = 0; i < 3; i++) {
        k_gemm<<<1024, 256, 0, stream>>>(Wg + i * 64 * 64, bg + i * 64, dinv,
                                         bufA, bufB, N);
        k_edge<<<(E + 3) / 4, 256, 0, stream>>>(src, dst, dinv, bufB, bufA, E);
        k_stats<<<512, 256, 0, stream>>>(bufA, stats + i * 128, N);
        k_norm<<<(N * 64 + 255) / 256, 256, 0, stream>>>(
            bufA, stats + i * 128, gamma + i * 64, beta + i * 64, N * 64, invN,
            (i < 2) ? 1 : 0);
    }
    k_cls<<<2048, 256, 0, stream>>>(bufA, W1, b1, W2, b2, out, N);
}

// Round 2
// 1171.952 us; speedup vs baseline: 2.2749x; 2.2749x over previous
//
#include <hip/hip_runtime.h>

#define EPSV 1e-5f

// ================= CSR build =================

// deg[dst] += 1 (int)
__global__ __launch_bounds__(256) void k_count(const int* __restrict__ dst,
                                               int* __restrict__ deg, int E) {
    int i = blockIdx.x * 256 + threadIdx.x;
    if (i < E) atomicAdd(&deg[dst[i]], 1);
}

// dinv = rsqrt(deg + 1) (self loop)
__global__ __launch_bounds__(256) void k_dinv(const int* __restrict__ deg,
                                              float* __restrict__ dinv, int N) {
    int i = blockIdx.x * 256 + threadIdx.x;
    if (i < N) dinv[i] = rsqrtf((float)deg[i] + 1.0f);
}

// scan phase 1: per-1024-chunk exclusive scan + chunk totals
__global__ __launch_bounds__(256) void k_scan1(const int* __restrict__ deg,
                                               int* __restrict__ rowptr,
                                               int* __restrict__ bsum, int N) {
    int t = threadIdx.x;
    int idx = blockIdx.x * 1024 + t * 4;
    int v[4], s = 0;
#pragma unroll
    for (int k = 0; k < 4; k++) { v[k] = (idx + k < N) ? deg[idx + k] : 0; s += v[k]; }
    __shared__ int ls[256];
    ls[t] = s;
    __syncthreads();
    for (int off = 1; off < 256; off <<= 1) {
        int x = (t >= off) ? ls[t - off] : 0;
        __syncthreads();
        ls[t] += x;
        __syncthreads();
    }
    if (t == 255) bsum[blockIdx.x] = ls[255];
    int run = (t == 0) ? 0 : ls[t - 1];
#pragma unroll
    for (int k = 0; k < 4; k++) {
        if (idx + k < N) rowptr[idx + k] = run;
        run += v[k];
    }
}

// scan phase 2: exclusive scan of chunk totals (B <= 256)
__global__ __launch_bounds__(256) void k_scan2(int* __restrict__ bsum, int B) {
    int t = threadIdx.x;
    __shared__ int ls[256];
    ls[t] = (t < B) ? bsum[t] : 0;
    __syncthreads();
    for (int off = 1; off < 256; off <<= 1) {
        int x = (t >= off) ? ls[t - off] : 0;
        __syncthreads();
        ls[t] += x;
        __syncthreads();
    }
    if (t < B) bsum[t] = (t == 0) ? 0 : ls[t - 1];
}

// scan phase 3: add chunk offsets
__global__ __launch_bounds__(256) void k_scan3(int* __restrict__ rowptr,
                                               const int* __restrict__ bsum, int N) {
    int i = blockIdx.x * 256 + threadIdx.x;
    if (i < N) rowptr[i] += bsum[i >> 10];
}

// scatter edges into CSR buckets; rowptr doubles as cursor, ends up = row ends
__global__ __launch_bounds__(256) void k_fill(const int* __restrict__ src,
                                              const int* __restrict__ dst,
                                              int* __restrict__ cursor,
                                              int* __restrict__ colidx, int E) {
    int i = blockIdx.x * 256 + threadIdx.x;
    if (i < E) {
        int pos = atomicAdd(&cursor[dst[i]], 1);
        colidx[pos] = src[i];
    }
}

// ================= network =================

// h0 = relu(x @ W_in + b_in); wave per node, lane = out feature
__global__ __launch_bounds__(256) void k_input(const float* __restrict__ x,
                                               const float* __restrict__ Win,
                                               const float* __restrict__ bin,
                                               float* __restrict__ h, int N) {
    int t = blockIdx.x * 256 + threadIdx.x;
    int node = t >> 6, j = t & 63;
    if (node >= N) return;
    const float* xr = x + node * 12;
    float acc = bin[j];
#pragma unroll
    for (int k = 0; k < 12; k++) acc = fmaf(xr[k], Win[k * 64 + j], acc);
    h[t] = fmaxf(acc, 0.0f);
}

// in place: h <- (h @ W) * dinv[node]   (pre-scaled hlin')
__global__ __launch_bounds__(256) void k_gemm(const float* __restrict__ W,
                                              const float* __restrict__ dinv,
                                              float* __restrict__ h, int N) {
    int j = threadIdx.x & 63;
    float w[64];
#pragma unroll
    for (int k = 0; k < 64; k++) w[k] = W[k * 64 + j];
    int wave = (blockIdx.x * 256 + threadIdx.x) >> 6;
    int nw = (gridDim.x * 256) >> 6;
    for (int node = wave; node < N; node += nw) {
        const float4* row = (const float4*)(h + node * 64);
        float acc = 0.0f;
#pragma unroll
        for (int kk = 0; kk < 16; kk++) {
            float4 r = row[kk];
            acc = fmaf(r.x, w[4 * kk + 0], acc);
            acc = fmaf(r.y, w[4 * kk + 1], acc);
            acc = fmaf(r.z, w[4 * kk + 2], acc);
            acc = fmaf(r.w, w[4 * kk + 3], acc);
        }
        h[node * 64 + j] = acc * dinv[node];
    }
}

// gather aggregation: out[d] = dinv[d]*(hl[d] + sum_{s in in(d)} hl[s]) + b
// wave per row, lane = feature. rowptr[d] = end of row d (start = rowptr[d-1]).
__global__ __launch_bounds__(256) void k_agg(const int* __restrict__ rowptr,
                                             const int* __restrict__ colidx,
                                             const float* __restrict__ dinv,
                                             const float* __restrict__ hl,
                                             const float* __restrict__ b,
                                             float* __restrict__ out, int N) {
    int d = (blockIdx.x * 256 + threadIdx.x) >> 6;
    int lane = threadIdx.x & 63;
    if (d >= N) return;
    int e0 = d ? rowptr[d - 1] : 0;
    int e1 = rowptr[d];
    float a0 = hl[d * 64 + lane], a1 = 0.0f, a2 = 0.0f, a3 = 0.0f;
    int e = e0;
    for (; e + 4 <= e1; e += 4) {
        int s0 = colidx[e], s1 = colidx[e + 1], s2 = colidx[e + 2], s3 = colidx[e + 3];
        a0 += hl[s0 * 64 + lane];
        a1 += hl[s1 * 64 + lane];
        a2 += hl[s2 * 64 + lane];
        a3 += hl[s3 * 64 + lane];
    }
    for (; e < e1; ++e) a0 += hl[colidx[e] * 64 + lane];
    float acc = (a0 + a1) + (a2 + a3);
    out[d * 64 + lane] = fmaf(acc, dinv[d], b[lane]);
}

// ---- fallback path (atomic scatter), used if ws_size is too small ----
__global__ __launch_bounds__(256) void k_gemm_fb(const float* __restrict__ W,
                                                 const float* __restrict__ b,
                                                 const float* __restrict__ dinv,
                                                 float* __restrict__ h,
                                                 float* __restrict__ hlin, int N) {
    int j = threadIdx.x & 63;
    float w[64];
#pragma unroll
    for (int k = 0; k < 64; k++) w[k] = W[k * 64 + j];
    float bj = b[j];
    int wave = (blockIdx.x * 256 + threadIdx.x) >> 6;
    int nw = (gridDim.x * 256) >> 6;
    for (int node = wave; node < N; node += nw) {
        const float4* row = (const float4*)(h + node * 64);
        float acc = 0.0f;
#pragma unroll
        for (int kk = 0; kk < 16; kk++) {
            float4 r = row[kk];
            acc = fmaf(r.x, w[4 * kk + 0], acc);
            acc = fmaf(r.y, w[4 * kk + 1], acc);
            acc = fmaf(r.z, w[4 * kk + 2], acc);
            acc = fmaf(r.w, w[4 * kk + 3], acc);
        }
        float dv = dinv[node];
        hlin[node * 64 + j] = acc;
        h[node * 64 + j] = fmaf(acc, dv * dv, bj);
    }
}

__global__ __launch_bounds__(256) void k_edge(const int* __restrict__ src,
                                              const int* __restrict__ dst,
                                              const float* __restrict__ dinv,
                                              const float* __restrict__ hlin,
                                              float* __restrict__ agg, int E) {
    int wave = (blockIdx.x * 256 + threadIdx.x) >> 6;
    int lane = threadIdx.x & 63;
    if (wave >= E) return;
    int s = src[wave], d = dst[wave];
    float nrm = dinv[s] * dinv[d];
    float v = hlin[s * 64 + lane];
    unsafeAtomicAdd(&agg[d * 64 + lane], v * nrm);
}

// ---- BN stats: per-feature sum and sum-of-squares ----
__global__ __launch_bounds__(256) void k_stats(const float* __restrict__ h,
                                               float* __restrict__ stats, int N) {
    int j = threadIdx.x & 63, grp = threadIdx.x >> 6;
    float s = 0.0f, s2 = 0.0f;
    for (int node = blockIdx.x * 4 + grp; node < N; node += gridDim.x * 4) {
        float v = h[node * 64 + j];
        s += v;
        s2 = fmaf(v, v, s2);
    }
    __shared__ float ls[8][64];
    ls[grp][j] = s;
    ls[4 + grp][j] = s2;
    __syncthreads();
    if (threadIdx.x < 64) {
        float a = ls[0][j] + ls[1][j] + ls[2][j] + ls[3][j];
        float a2 = ls[4][j] + ls[5][j] + ls[6][j] + ls[7][j];
        unsafeAtomicAdd(&stats[j], a);
        unsafeAtomicAdd(&stats[64 + j], a2);
    }
}

// ---- BN normalize (+ optional relu), in place ----
__global__ __launch_bounds__(256) void k_norm(float* __restrict__ h,
                                              const float* __restrict__ stats,
                                              const float* __restrict__ gamma,
                                              const float* __restrict__ beta,
                                              int total, float invN, int relu) {
    int t = blockIdx.x * 256 + threadIdx.x;
    if (t >= total) return;
    int j = t & 63;
    float mu = stats[j] * invN;
    float var = fmaf(-mu, mu, stats[64 + j] * invN);
    float sc = rsqrtf(var + EPSV) * gamma[j];
    float v = fmaf(h[t] - mu, sc, beta[j]);
    if (relu) v = fmaxf(v, 0.0f);
    h[t] = v;
}

// ---- classifier: out = relu(h@W1+b1) @ W2 + b2 ----
__global__ __launch_bounds__(256) void k_cls(const float* __restrict__ h,
                                             const float* __restrict__ W1,
                                             const float* __restrict__ b1,
                                             const float* __restrict__ W2,
                                             const float* __restrict__ b2,
                                             float* __restrict__ out, int N) {
    int lane = threadIdx.x & 63;
    int half = lane >> 5, jj = lane & 31;
    float w[64];
#pragma unroll
    for (int k = 0; k < 64; k++) w[k] = W1[k * 32 + jj];
    float bj = b1[jj];
    float w20 = W2[jj * 2 + 0], w21 = W2[jj * 2 + 1];
    float b20 = b2[0], b21 = b2[1];
    int wave = (blockIdx.x * 256 + threadIdx.x) >> 6;
    int nw = (gridDim.x * 256) >> 6;
    for (int base = wave * 2; base < N; base += nw * 2) {
        int node = base + half;
        int vnode = node < N ? node : 0;
        const float4* row = (const float4*)(h + vnode * 64);
        float acc = bj;
#pragma unroll
        for (int kk = 0; kk < 16; kk++) {
            float4 r = row[kk];
            acc = fmaf(r.x, w[4 * kk + 0], acc);
            acc = fmaf(r.y, w[4 * kk + 1], acc);
            acc = fmaf(r.z, w[4 * kk + 2], acc);
            acc = fmaf(r.w, w[4 * kk + 3], acc);
        }
        float h2 = fmaxf(acc, 0.0f);
        float t0 = h2 * w20, t1 = h2 * w21;
#pragma unroll
        for (int m = 1; m <= 16; m <<= 1) {
            t0 += __shfl_xor(t0, m, 64);
            t1 += __shfl_xor(t1, m, 64);
        }
        if (jj == 0 && node < N) {
            ((float2*)out)[node] = make_float2(t0 + b20, t1 + b21);
        }
    }
}

extern "C" void kernel_launch(void* const* d_in, const int* in_sizes, int n_in,
                              void* d_out, int out_size, void* d_ws, size_t ws_size,
                              hipStream_t stream) {
    const float* x     = (const float*)d_in[0];
    const int*   ei    = (const int*)d_in[1];
    const float* Win   = (const float*)d_in[2];
    const float* bin   = (const float*)d_in[3];
    const float* Wg    = (const float*)d_in[4];
    const float* bg    = (const float*)d_in[5];
    const float* gamma = (const float*)d_in[6];
    const float* beta  = (const float*)d_in[7];
    const float* W1    = (const float*)d_in[8];
    const float* b1    = (const float*)d_in[9];
    const float* W2    = (const float*)d_in[10];
    const float* b2    = (const float*)d_in[11];
    float* out = (float*)d_out;

    int N = in_sizes[0] / 12;
    int E = in_sizes[1] / 2;
    const int* src = ei;
    const int* dst = ei + E;
    float invN = 1.0f / (float)N;

    char* ws = (char*)d_ws;
    size_t szh = (size_t)N * 64 * sizeof(float);
    size_t szE = ((size_t)E * sizeof(int) + 255) / 256 * 256;
    size_t szN = ((size_t)N * sizeof(int) + 255) / 256 * 256;
    size_t need = 2 * szh + szE + 3 * szN + 4096 + 2048;

    if (ws_size >= need) {
        // ---- CSR gather path ----
        float* bufA  = (float*)ws;
        float* bufB  = (float*)(ws + szh);
        int* colidx  = (int*)(ws + 2 * szh);
        int* deg     = (int*)(ws + 2 * szh + szE);
        int* rowptr  = (int*)(ws + 2 * szh + szE + szN);
        float* dinv  = (float*)(ws + 2 * szh + szE + 2 * szN);
        int* bsum    = (int*)(ws + 2 * szh + szE + 3 * szN);
        float* stats = (float*)(ws + 2 * szh + szE + 3 * szN + 4096);

        hipMemsetAsync(deg, 0, (size_t)N * sizeof(int), stream);
        hipMemsetAsync(stats, 0, 3 * 128 * sizeof(float), stream);

        k_count<<<(E + 255) / 256, 256, 0, stream>>>(dst, deg, E);
        k_dinv<<<(N + 255) / 256, 256, 0, stream>>>(deg, dinv, N);
        int B = (N + 1023) / 1024;
        k_scan1<<<B, 256, 0, stream>>>(deg, rowptr, bsum, N);
        k_scan2<<<1, 256, 0, stream>>>(bsum, B);
        k_scan3<<<(N + 255) / 256, 256, 0, stream>>>(rowptr, bsum, N);
        k_fill<<<(E + 255) / 256, 256, 0, stream>>>(src, dst, rowptr, colidx, E);

        k_input<<<(N * 64 + 255) / 256, 256, 0, stream>>>(x, Win, bin, bufA, N);

        float* cur = bufA;
        float* oth = bufB;
        for (int i = 0; i < 3; i++) {
            k_gemm<<<1024, 256, 0, stream>>>(Wg + i * 64 * 64, dinv, cur, N);
            k_agg<<<(N + 3) / 4, 256, 0, stream>>>(rowptr, colidx, dinv, cur,
                                                   bg + i * 64, oth, N);
            k_stats<<<512, 256, 0, stream>>>(oth, stats + i * 128, N);
            k_norm<<<(N * 64 + 255) / 256, 256, 0, stream>>>(
                oth, stats + i * 128, gamma + i * 64, beta + i * 64, N * 64, invN,
                (i < 2) ? 1 : 0);
            float* t = cur; cur = oth; oth = t;
        }
        k_cls<<<2048, 256, 0, stream>>>(cur, W1, b1, W2, b2, out, N);
    } else {
        // ---- fallback: round-1 atomic scatter path ----
        float* bufA  = (float*)ws;
        float* bufB  = (float*)(ws + szh);
        int* deg     = (int*)(ws + 2 * szh);
        float* dinv  = (float*)(ws + 2 * szh + szN);
        float* stats = (float*)(ws + 2 * szh + 2 * szN);

        hipMemsetAsync(deg, 0, (size_t)N * sizeof(int), stream);
        hipMemsetAsync(stats, 0, 3 * 128 * sizeof(float), stream);

        k_count<<<(E + 255) / 256, 256, 0, stream>>>(dst, deg, E);
        k_dinv<<<(N + 255) / 256, 256, 0, stream>>>(deg, dinv, N);
        k_input<<<(N * 64 + 255) / 256, 256, 0, stream>>>(x, Win, bin, bufA, N);

        for (int i = 0; i < 3; i++) {
            k_gemm_fb<<<1024, 256, 0, stream>>>(Wg + i * 64 * 64, bg + i * 64, dinv,
                                                bufA, bufB, N);
            k_edge<<<(E + 3) / 4, 256, 0, stream>>>(src, dst, dinv, bufB, bufA, E);
            k_stats<<<512, 256, 0, stream>>>(bufA, stats + i * 128, N);
            k_norm<<<(N * 64 + 255) / 256, 256, 0, stream>>>(
                bufA, stats + i * 128, gamma + i * 64, beta + i * 64, N * 64, invN,
                (i < 2) ? 1 : 0);
        }
        k_cls<<<2048, 256, 0, stream>>>(bufA, W1, b1, W2, b2, out, N);
    }
}